// Round 8
// baseline (222.565 us; speedup 1.0000x reference)
//
#include <hip/hip_runtime.h>

// ---- types ----
typedef __bf16 bf16x8 __attribute__((ext_vector_type(8)));
typedef float  f32x4  __attribute__((ext_vector_type(4)));
typedef float  f32x16 __attribute__((ext_vector_type(16)));
typedef unsigned int uint32x4 __attribute__((ext_vector_type(4)));

__device__ __forceinline__ short f2bf(float f) {
  union { float f; unsigned u; } v; v.f = f;
  unsigned r = v.u + 0x7fffu + ((v.u >> 16) & 1u);
  return (short)(r >> 16);
}

// async global->LDS (16B per lane); LDS dest must be wave-uniform base + lane*16
__device__ __forceinline__ void gl_lds16(const short* g, short* l) {
  __builtin_amdgcn_global_load_lds((const __attribute__((address_space(1))) void*)g,
                                   (__attribute__((address_space(3))) void*)l, 16, 0, 0);
}

// ---- cast x fp32 -> bf16 (vectorized) ----
__global__ __launch_bounds__(256) void cast_x_kernel(const float* __restrict__ in,
                                                     short* __restrict__ out, int n4) {
  int i = blockIdx.x * 256 + threadIdx.x;
  if (i >= n4) return;
  float4 f = reinterpret_cast<const float4*>(in)[i];
  short4 o;
  o.x = f2bf(f.x); o.y = f2bf(f.y); o.z = f2bf(f.z); o.w = f2bf(f.w);
  reinterpret_cast<short4*>(out)[i] = o;
}

// ---- transpose + cast: in[R][Cc] fp32 -> out[Cc][R] bf16 ----
__global__ __launch_bounds__(256) void transpose_cast(const float* __restrict__ in,
                                                      short* __restrict__ out, int R, int Cc) {
  __shared__ short tile[64][65];
  int bx = blockIdx.x * 64;
  int by = blockIdx.y * 64;
  int tx = threadIdx.x & 63, ty = threadIdx.x >> 6;
  #pragma unroll
  for (int i = ty; i < 64; i += 4)
    tile[i][tx] = f2bf(in[(size_t)(by + i) * Cc + bx + tx]);
  __syncthreads();
  #pragma unroll
  for (int i = ty; i < 64; i += 4)
    out[(size_t)(bx + i) * R + by + tx] = tile[tx][i];
}

// ---- GEMM1: qkv = x_bf[4096][1024] * Wqkv_t[3072][1024]^T + bqkv
//      q,k -> [B2][H16][T2048][D64] bf16 (q scaled 0.125*log2e); v -> [BH][D64][T2048]
__global__ __launch_bounds__(256) void gemm_qkv(const short* __restrict__ A,
                                                const short* __restrict__ Bt,
                                                const float* __restrict__ bias,
                                                short* __restrict__ qo,
                                                short* __restrict__ ko,
                                                short* __restrict__ vt) {
  const int K = 1024;
  __shared__ short Al[8192];   // linear [128][64]
  __shared__ short Bl[8192];
  int tid = threadIdx.x;
  int mtile = blockIdx.y * 128, ntile = blockIdx.x * 128;
  int w = tid >> 6, l = tid & 63;
  int wr = w >> 1, wc = w & 1;
  int lr = l & 15, lg = l >> 4;

  f32x4 zero4 = {0.f, 0.f, 0.f, 0.f};
  f32x4 acc[4][4];
  #pragma unroll
  for (int i = 0; i < 4; ++i)
    #pragma unroll
    for (int j = 0; j < 4; ++j) acc[i][j] = zero4;

  for (int k0 = 0; k0 < K; k0 += 64) {
    __syncthreads();
    #pragma unroll
    for (int c = 0; c < 4; ++c) {
      int idx = tid + c * 256;
      int row = idx >> 3, kc = idx & 7;
      gl_lds16(&A[(size_t)(mtile + row) * K + k0 + kc * 8], &Al[idx * 8]);
      gl_lds16(&Bt[(size_t)(ntile + row) * K + k0 + kc * 8], &Bl[idx * 8]);
    }
    __syncthreads();
    __builtin_amdgcn_s_setprio(1);
    #pragma unroll
    for (int kk = 0; kk < 2; ++kk) {
      bf16x8 af[4], bfr[4];
      #pragma unroll
      for (int i = 0; i < 4; ++i)
        af[i] = *reinterpret_cast<const bf16x8*>(&Al[(wr * 64 + i * 16 + lr) * 64 + kk * 32 + lg * 8]);
      #pragma unroll
      for (int j = 0; j < 4; ++j)
        bfr[j] = *reinterpret_cast<const bf16x8*>(&Bl[(wc * 64 + j * 16 + lr) * 64 + kk * 32 + lg * 8]);
      #pragma unroll
      for (int i = 0; i < 4; ++i)
        #pragma unroll
        for (int j = 0; j < 4; ++j)
          acc[i][j] = __builtin_amdgcn_mfma_f32_16x16x32_bf16(af[i], bfr[j], acc[i][j], 0, 0, 0);
    }
    __builtin_amdgcn_s_setprio(0);
  }

  #pragma unroll
  for (int j = 0; j < 4; ++j) {
    int n = ntile + wc * 64 + j * 16 + lr;   // 0..3071 (sec uniform per block)
    float bv = bias[n];
    int sec = n >> 10;
    int ch = n & 1023;
    int h = ch >> 6, d = ch & 63;
    if (sec == 2) {
      #pragma unroll
      for (int i = 0; i < 4; ++i) {
        int t0g = mtile + wr * 64 + i * 16 + lg * 4;
        int bb = t0g >> 11, t = t0g & 2047;
        short4 pk;
        pk.x = f2bf(acc[i][j][0] + bv);
        pk.y = f2bf(acc[i][j][1] + bv);
        pk.z = f2bf(acc[i][j][2] + bv);
        pk.w = f2bf(acc[i][j][3] + bv);
        *reinterpret_cast<short4*>(&vt[((size_t)(bb * 16 + h) * 64 + d) * 2048 + t]) = pk;
      }
    } else {
      short* dst = (sec == 0) ? qo : ko;
      // q scaled by (1/sqrt(64)) * log2(e) so attention works in exp2 domain
      float sc = (sec == 0) ? 0.18033688f : 1.0f;
      #pragma unroll
      for (int i = 0; i < 4; ++i) {
        #pragma unroll
        for (int r = 0; r < 4; ++r) {
          int m = mtile + wr * 64 + i * 16 + lg * 4 + r;
          int bb = m >> 11, t = m & 2047;
          dst[(size_t)((bb * 16 + h) * 2048 + t) * 64 + d] = f2bf((acc[i][j][r] + bv) * sc);
        }
      }
    }
  }
}

// ---- flash attention v7: v6 + register-pipelined K (double-buffer) and
//      step-entry V loads; 4 waves/block kv-split, LDS merge ----
__device__ __forceinline__ void load_k4(uint4* kr, const short* kp) {
  kr[0] = *reinterpret_cast<const uint4*>(kp);
  kr[1] = *reinterpret_cast<const uint4*>(kp + 16);
  kr[2] = *reinterpret_cast<const uint4*>(kp + 32);
  kr[3] = *reinterpret_cast<const uint4*>(kp + 48);
}

__device__ __forceinline__ void attn_compute(const uint4* kr, const short* __restrict__ vp,
                                             const bf16x8* qf,
                                             f32x16& y0, f32x16& y1,
                                             float& m, float& li,
                                             int lq, int hl, bool diag) {
  // issue V loads immediately (consumed ~QK+softmax later)
  uint4 vr0 = *reinterpret_cast<const uint4*>(vp);
  uint4 vr1 = *reinterpret_cast<const uint4*>(vp + 16);
  uint4 vr2 = *reinterpret_cast<const uint4*>(vp + 32 * 2048);
  uint4 vr3 = *reinterpret_cast<const uint4*>(vp + 32 * 2048 + 16);

  f32x16 s;
  #pragma unroll
  for (int r = 0; r < 16; ++r) s[r] = 0.f;
  __builtin_amdgcn_s_setprio(1);
  #pragma unroll
  for (int ks = 0; ks < 4; ++ks) {
    bf16x8 kf = __builtin_bit_cast(bf16x8, kr[ks]);
    s = __builtin_amdgcn_mfma_f32_32x32x16_bf16(kf, qf[ks], s, 0, 0, 0);
  }
  __builtin_amdgcn_s_setprio(0);
  if (diag) {
    #pragma unroll
    for (int r = 0; r < 16; ++r) {
      int kvl = (r & 3) + 8 * (r >> 2) + 4 * hl;
      if (kvl > lq) s[r] = -1e30f;
    }
  }
  float a0 = fmaxf(fmaxf(s[0], s[1]), fmaxf(s[2], s[3]));
  float a1 = fmaxf(fmaxf(s[4], s[5]), fmaxf(s[6], s[7]));
  float a2 = fmaxf(fmaxf(s[8], s[9]), fmaxf(s[10], s[11]));
  float a3 = fmaxf(fmaxf(s[12], s[13]), fmaxf(s[14], s[15]));
  float pm = fmaxf(fmaxf(a0, a1), fmaxf(a2, a3));
  pm = fmaxf(pm, __shfl_xor(pm, 32));
  if (!__all(pm - m <= 8.0f)) {
    float mn = fmaxf(m, pm);
    float sc = __builtin_amdgcn_exp2f(m - mn);
    m = mn;
    li *= sc;
    #pragma unroll
    for (int r = 0; r < 16; ++r) { y0[r] *= sc; y1[r] *= sc; }
  }
  unsigned u[8];
  float rs = 0.f;
  #pragma unroll
  for (int rq = 0; rq < 4; ++rq) {
    float p0 = __builtin_amdgcn_exp2f(s[4 * rq + 0] - m);
    float p1 = __builtin_amdgcn_exp2f(s[4 * rq + 1] - m);
    float p2 = __builtin_amdgcn_exp2f(s[4 * rq + 2] - m);
    float p3 = __builtin_amdgcn_exp2f(s[4 * rq + 3] - m);
    rs += (p0 + p1) + (p2 + p3);
    asm("v_cvt_pk_bf16_f32 %0, %1, %2" : "=v"(u[rq * 2 + 0]) : "v"(p0), "v"(p1));
    asm("v_cvt_pk_bf16_f32 %0, %1, %2" : "=v"(u[rq * 2 + 1]) : "v"(p2), "v"(p3));
  }
  rs += __shfl_xor(rs, 32);
  li += rs;
  asm volatile("v_permlane32_swap_b32 %0, %1" : "+v"(u[0]), "+v"(u[2]));
  asm volatile("v_permlane32_swap_b32 %0, %1" : "+v"(u[1]), "+v"(u[3]));
  asm volatile("v_permlane32_swap_b32 %0, %1" : "+v"(u[4]), "+v"(u[6]));
  asm volatile("v_permlane32_swap_b32 %0, %1" : "+v"(u[5]), "+v"(u[7]));
  uint32x4 w0 = {u[0], u[1], u[2], u[3]};
  uint32x4 w1 = {u[4], u[5], u[6], u[7]};
  bf16x8 pa0 = __builtin_bit_cast(bf16x8, w0);
  bf16x8 pa1 = __builtin_bit_cast(bf16x8, w1);
  __builtin_amdgcn_s_setprio(1);
  {
    bf16x8 vf00 = __builtin_bit_cast(bf16x8, vr0);
    bf16x8 vf01 = __builtin_bit_cast(bf16x8, vr1);
    bf16x8 vf10 = __builtin_bit_cast(bf16x8, vr2);
    bf16x8 vf11 = __builtin_bit_cast(bf16x8, vr3);
    y0 = __builtin_amdgcn_mfma_f32_32x32x16_bf16(vf00, pa0, y0, 0, 0, 0);
    y0 = __builtin_amdgcn_mfma_f32_32x32x16_bf16(vf01, pa1, y0, 0, 0, 0);
    y1 = __builtin_amdgcn_mfma_f32_32x32x16_bf16(vf10, pa0, y1, 0, 0, 0);
    y1 = __builtin_amdgcn_mfma_f32_32x32x16_bf16(vf11, pa1, y1, 0, 0, 0);
  }
  __builtin_amdgcn_s_setprio(0);
}

__global__ __launch_bounds__(256, 4) void attn_kernel(const short* __restrict__ q,
                                                      const short* __restrict__ k,
                                                      const short* __restrict__ vt,
                                                      short* __restrict__ y) {
  __shared__ float partL[3][8][64][4];   // 24 KB: partials of waves 1..3
  __shared__ float stm[4][32], stl[4][32];
  const int bid = blockIdx.x;
  const int t = 63 - (bid >> 5);           // longest-first
  const int b5 = bid & 31;
  const int bh = (b5 & 7) * 4 + (b5 >> 3); // group each bh's blocks on one XCD
  const int tid = threadIdx.x;
  const int w = tid >> 6;                  // wave: kv-split index 0..3
  const int l = tid & 63;
  const int lq = l & 31, hl = l >> 5;
  const short* qb = q + (size_t)bh * 131072;
  const short* kb = k + (size_t)bh * 131072;
  const short* vb = vt + (size_t)bh * 131072;   // [64][2048]

  // Q B-frags (k=64 -> 4 frags), shared q-tile for all 4 waves
  bf16x8 qf[4];
  {
    const short* qp = &qb[(size_t)(32 * t + lq) * 64 + hl * 8];
    #pragma unroll
    for (int ks = 0; ks < 4; ++ks)
      qf[ks] = *reinterpret_cast<const bf16x8*>(qp + ks * 16);
  }

  f32x16 y0, y1;
  #pragma unroll
  for (int r = 0; r < 16; ++r) { y0[r] = 0.f; y1[r] = 0.f; }
  float m = -1e30f, li = 0.f;

  // wave w handles kv tiles {w, w+4, ...} < t, plus diag tile t if t&3==w
  const short* kb0 = kb + (size_t)lq * 64 + hl * 8;   // + tile*2048
  const short* vb0 = vb + (size_t)lq * 2048 + hl * 8; // + tile*32
  const int cnt = (t > w) ? ((t - w + 3) >> 2) : 0;   // non-diag tiles
  const bool hd = ((t & 3) == w);
  const int n = cnt + (hd ? 1 : 0);

  uint4 KA[4], KB[4];
  if (n > 0) {
    int t0 = (0 < cnt) ? w : t;
    load_k4(KA, kb0 + (size_t)t0 * 2048);
  }
  int i = 0;
  while (i < n) {
    if (i + 1 < n) {
      int tn = (i + 1 < cnt) ? (w + 4 * (i + 1)) : t;
      load_k4(KB, kb0 + (size_t)tn * 2048);
    }
    {
      int tc = (i < cnt) ? (w + 4 * i) : t;
      attn_compute(KA, vb0 + tc * 32, qf, y0, y1, m, li, lq, hl, hd && (i == n - 1));
    }
    ++i;
    if (i >= n) break;
    if (i + 1 < n) {
      int tn = (i + 1 < cnt) ? (w + 4 * (i + 1)) : t;
      load_k4(KA, kb0 + (size_t)tn * 2048);
    }
    {
      int tc = (i < cnt) ? (w + 4 * i) : t;
      attn_compute(KB, vb0 + tc * 32, qf, y0, y1, m, li, lq, hl, hd && (i == n - 1));
    }
    ++i;
  }

  // ---- merge the 4 wave-partials ----
  if (hl == 0) { stm[w][lq] = m; stl[w][lq] = li; }
  __syncthreads();
  float m0 = stm[0][lq], m1 = stm[1][lq], m2 = stm[2][lq], m3 = stm[3][lq];
  float M = fmaxf(fmaxf(m0, m1), fmaxf(m2, m3));
  float L = stl[0][lq] * __builtin_amdgcn_exp2f(m0 - M) +
            stl[1][lq] * __builtin_amdgcn_exp2f(m1 - M) +
            stl[2][lq] * __builtin_amdgcn_exp2f(m2 - M) +
            stl[3][lq] * __builtin_amdgcn_exp2f(m3 - M);
  float sc = __builtin_amdgcn_exp2f(m - M);
  #pragma unroll
  for (int r = 0; r < 16; ++r) { y0[r] *= sc; y1[r] *= sc; }
  if (w > 0) {
    #pragma unroll
    for (int c = 0; c < 4; ++c) {
      f32x4 v0 = {y0[4 * c + 0], y0[4 * c + 1], y0[4 * c + 2], y0[4 * c + 3]};
      f32x4 v1 = {y1[4 * c + 0], y1[4 * c + 1], y1[4 * c + 2], y1[4 * c + 3]};
      *reinterpret_cast<f32x4*>(&partL[w - 1][c][l][0]) = v0;
      *reinterpret_cast<f32x4*>(&partL[w - 1][c + 4][l][0]) = v1;
    }
  }
  __syncthreads();
  if (w == 0) {
    #pragma unroll
    for (int o = 0; o < 3; ++o)
      #pragma unroll
      for (int c = 0; c < 4; ++c) {
        f32x4 v0 = *reinterpret_cast<const f32x4*>(&partL[o][c][l][0]);
        f32x4 v1 = *reinterpret_cast<const f32x4*>(&partL[o][c + 4][l][0]);
        #pragma unroll
        for (int r = 0; r < 4; ++r) { y0[4 * c + r] += v0[r]; y1[4 * c + r] += v1[r]; }
      }
    float inv = 1.0f / L;
    int b_ = bh >> 4, h_ = bh & 15;
    short* yrow = &y[(size_t)(b_ * 2048 + 32 * t + lq) * 1024 + h_ * 64];
    #pragma unroll
    for (int dt = 0; dt < 2; ++dt) {
      const f32x16& yy = dt ? y1 : y0;
      #pragma unroll
      for (int rq = 0; rq < 4; ++rq) {
        int d0 = dt * 32 + 8 * rq + 4 * hl;
        uint2 pk;
        pk.x = (unsigned)(unsigned short)f2bf(yy[4 * rq + 0] * inv) |
               ((unsigned)(unsigned short)f2bf(yy[4 * rq + 1] * inv) << 16);
        pk.y = (unsigned)(unsigned short)f2bf(yy[4 * rq + 2] * inv) |
               ((unsigned)(unsigned short)f2bf(yy[4 * rq + 3] * inv) << 16);
        *reinterpret_cast<uint2*>(yrow + d0) = pk;
      }
    }
  }
}

// ---- GEMM3: out fp32 = y_bf[4096][1024] * Wproj_t[1024][1024]^T + bproj ----
__global__ __launch_bounds__(256) void gemm_proj(const short* __restrict__ A,
                                                 const short* __restrict__ Bt,
                                                 const float* __restrict__ bias,
                                                 float* __restrict__ out) {
  const int K = 1024;
  __shared__ short Al[8192];
  __shared__ short Bl[8192];
  int tid = threadIdx.x;
  int mtile = blockIdx.y * 128, ntile = blockIdx.x * 128;
  int w = tid >> 6, l = tid & 63;
  int wr = w >> 1, wc = w & 1;
  int lr = l & 15, lg = l >> 4;

  f32x4 zero4 = {0.f, 0.f, 0.f, 0.f};
  f32x4 acc[4][4];
  #pragma unroll
  for (int i = 0; i < 4; ++i)
    #pragma unroll
    for (int j = 0; j < 4; ++j) acc[i][j] = zero4;

  for (int k0 = 0; k0 < K; k0 += 64) {
    __syncthreads();
    #pragma unroll
    for (int c = 0; c < 4; ++c) {
      int idx = tid + c * 256;
      int row = idx >> 3, kc = idx & 7;
      gl_lds16(&A[(size_t)(mtile + row) * K + k0 + kc * 8], &Al[idx * 8]);
      gl_lds16(&Bt[(size_t)(ntile + row) * K + k0 + kc * 8], &Bl[idx * 8]);
    }
    __syncthreads();
    __builtin_amdgcn_s_setprio(1);
    #pragma unroll
    for (int kk = 0; kk < 2; ++kk) {
      bf16x8 af[4], bfr[4];
      #pragma unroll
      for (int i = 0; i < 4; ++i)
        af[i] = *reinterpret_cast<const bf16x8*>(&Al[(wr * 64 + i * 16 + lr) * 64 + kk * 32 + lg * 8]);
      #pragma unroll
      for (int j = 0; j < 4; ++j)
        bfr[j] = *reinterpret_cast<const bf16x8*>(&Bl[(wc * 64 + j * 16 + lr) * 64 + kk * 32 + lg * 8]);
      #pragma unroll
      for (int i = 0; i < 4; ++i)
        #pragma unroll
        for (int j = 0; j < 4; ++j)
          acc[i][j] = __builtin_amdgcn_mfma_f32_16x16x32_bf16(af[i], bfr[j], acc[i][j], 0, 0, 0);
    }
    __builtin_amdgcn_s_setprio(0);
  }

  #pragma unroll
  for (int j = 0; j < 4; ++j) {
    int n = ntile + wc * 64 + j * 16 + lr;
    float bv = bias[n];
    #pragma unroll
    for (int i = 0; i < 4; ++i) {
      #pragma unroll
      for (int r = 0; r < 4; ++r) {
        int m = mtile + wr * 64 + i * 16 + lg * 4 + r;
        out[(size_t)m * 1024 + n] = acc[i][j][r] + bv;
      }
    }
  }
}

extern "C" void kernel_launch(void* const* d_in, const int* in_sizes, int n_in,
                              void* d_out, int out_size, void* d_ws, size_t ws_size,
                              hipStream_t stream) {
  const float* x     = (const float*)d_in[0];
  const float* Wqkv  = (const float*)d_in[1];
  const float* bqkv  = (const float*)d_in[2];
  const float* Wproj = (const float*)d_in[3];
  const float* bproj = (const float*)d_in[4];
  float* out = (float*)d_out;

  const size_t M4 = 4096ull * 1024ull;
  short* ws = (short*)d_ws;
  short* x_bf    = ws;
  short* wqkv_t  = ws + M4;
  short* wproj_t = ws + M4 + 3ull * 1024 * 1024;
  short* qb      = wproj_t + 1024ull * 1024;
  short* kb      = qb + M4;
  short* vtb     = kb + M4;     // [bh][64][2048] transposed V
  short* yb      = x_bf;        // alias: x_bf dead after gemm_qkv

  cast_x_kernel<<<4096, 256, 0, stream>>>(x, x_bf, (int)(M4 / 4));
  transpose_cast<<<dim3(48, 16), 256, 0, stream>>>(Wqkv, wqkv_t, 1024, 3072);
  transpose_cast<<<dim3(16, 16), 256, 0, stream>>>(Wproj, wproj_t, 1024, 1024);
  gemm_qkv<<<dim3(24, 32), 256, 0, stream>>>(x_bf, wqkv_t, bqkv, qb, kb, vtb);
  attn_kernel<<<2048, 256, 0, stream>>>(qb, kb, vtb, yb);
  gemm_proj<<<dim3(8, 32), 256, 0, stream>>>(yb, wproj_t, bproj, out);
}

// Round 9
// 168.568 us; speedup vs baseline: 1.3203x; 1.3203x over previous
//
#include <hip/hip_runtime.h>

// ---- types ----
typedef __bf16 bf16x8 __attribute__((ext_vector_type(8)));
typedef float  f32x4  __attribute__((ext_vector_type(4)));
typedef float  f32x16 __attribute__((ext_vector_type(16)));
typedef unsigned int uint32x4 __attribute__((ext_vector_type(4)));

__device__ __forceinline__ short f2bf(float f) {
  union { float f; unsigned u; } v; v.f = f;
  unsigned r = v.u + 0x7fffu + ((v.u >> 16) & 1u);
  return (short)(r >> 16);
}

// async global->LDS (16B per lane); LDS dest must be wave-uniform base + lane*16
__device__ __forceinline__ void gl_lds16(const short* g, short* l) {
  __builtin_amdgcn_global_load_lds((const __attribute__((address_space(1))) void*)g,
                                   (__attribute__((address_space(3))) void*)l, 16, 0, 0);
}

// ---- cast x fp32 -> bf16 (vectorized) ----
__global__ __launch_bounds__(256) void cast_x_kernel(const float* __restrict__ in,
                                                     short* __restrict__ out, int n4) {
  int i = blockIdx.x * 256 + threadIdx.x;
  if (i >= n4) return;
  float4 f = reinterpret_cast<const float4*>(in)[i];
  short4 o;
  o.x = f2bf(f.x); o.y = f2bf(f.y); o.z = f2bf(f.z); o.w = f2bf(f.w);
  reinterpret_cast<short4*>(out)[i] = o;
}

// ---- transpose + cast: in[R][Cc] fp32 -> out[Cc][R] bf16 ----
__global__ __launch_bounds__(256) void transpose_cast(const float* __restrict__ in,
                                                      short* __restrict__ out, int R, int Cc) {
  __shared__ short tile[64][65];
  int bx = blockIdx.x * 64;
  int by = blockIdx.y * 64;
  int tx = threadIdx.x & 63, ty = threadIdx.x >> 6;
  #pragma unroll
  for (int i = ty; i < 64; i += 4)
    tile[i][tx] = f2bf(in[(size_t)(by + i) * Cc + bx + tx]);
  __syncthreads();
  #pragma unroll
  for (int i = ty; i < 64; i += 4)
    out[(size_t)(bx + i) * R + by + tx] = tile[tx][i];
}

// ---- GEMM1: qkv = x_bf[4096][1024] * Wqkv_t[3072][1024]^T + bqkv
//      q,k -> [B2][H16][T2048][D64] bf16 (q scaled 0.125*log2e); v -> [BH][D64][T2048]
__global__ __launch_bounds__(256) void gemm_qkv(const short* __restrict__ A,
                                                const short* __restrict__ Bt,
                                                const float* __restrict__ bias,
                                                short* __restrict__ qo,
                                                short* __restrict__ ko,
                                                short* __restrict__ vt) {
  const int K = 1024;
  __shared__ short Al[8192];   // linear [128][64]
  __shared__ short Bl[8192];
  int tid = threadIdx.x;
  int mtile = blockIdx.y * 128, ntile = blockIdx.x * 128;
  int w = tid >> 6, l = tid & 63;
  int wr = w >> 1, wc = w & 1;
  int lr = l & 15, lg = l >> 4;

  f32x4 zero4 = {0.f, 0.f, 0.f, 0.f};
  f32x4 acc[4][4];
  #pragma unroll
  for (int i = 0; i < 4; ++i)
    #pragma unroll
    for (int j = 0; j < 4; ++j) acc[i][j] = zero4;

  for (int k0 = 0; k0 < K; k0 += 64) {
    __syncthreads();
    #pragma unroll
    for (int c = 0; c < 4; ++c) {
      int idx = tid + c * 256;
      int row = idx >> 3, kc = idx & 7;
      gl_lds16(&A[(size_t)(mtile + row) * K + k0 + kc * 8], &Al[idx * 8]);
      gl_lds16(&Bt[(size_t)(ntile + row) * K + k0 + kc * 8], &Bl[idx * 8]);
    }
    __syncthreads();
    __builtin_amdgcn_s_setprio(1);
    #pragma unroll
    for (int kk = 0; kk < 2; ++kk) {
      bf16x8 af[4], bfr[4];
      #pragma unroll
      for (int i = 0; i < 4; ++i)
        af[i] = *reinterpret_cast<const bf16x8*>(&Al[(wr * 64 + i * 16 + lr) * 64 + kk * 32 + lg * 8]);
      #pragma unroll
      for (int j = 0; j < 4; ++j)
        bfr[j] = *reinterpret_cast<const bf16x8*>(&Bl[(wc * 64 + j * 16 + lr) * 64 + kk * 32 + lg * 8]);
      #pragma unroll
      for (int i = 0; i < 4; ++i)
        #pragma unroll
        for (int j = 0; j < 4; ++j)
          acc[i][j] = __builtin_amdgcn_mfma_f32_16x16x32_bf16(af[i], bfr[j], acc[i][j], 0, 0, 0);
    }
    __builtin_amdgcn_s_setprio(0);
  }

  #pragma unroll
  for (int j = 0; j < 4; ++j) {
    int n = ntile + wc * 64 + j * 16 + lr;   // 0..3071 (sec uniform per block)
    float bv = bias[n];
    int sec = n >> 10;
    int ch = n & 1023;
    int h = ch >> 6, d = ch & 63;
    if (sec == 2) {
      #pragma unroll
      for (int i = 0; i < 4; ++i) {
        int t0g = mtile + wr * 64 + i * 16 + lg * 4;
        int bb = t0g >> 11, t = t0g & 2047;
        short4 pk;
        pk.x = f2bf(acc[i][j][0] + bv);
        pk.y = f2bf(acc[i][j][1] + bv);
        pk.z = f2bf(acc[i][j][2] + bv);
        pk.w = f2bf(acc[i][j][3] + bv);
        *reinterpret_cast<short4*>(&vt[((size_t)(bb * 16 + h) * 64 + d) * 2048 + t]) = pk;
      }
    } else {
      short* dst = (sec == 0) ? qo : ko;
      // q scaled by (1/sqrt(64)) * log2(e) so attention works in exp2 domain
      float sc = (sec == 0) ? 0.18033688f : 1.0f;
      #pragma unroll
      for (int i = 0; i < 4; ++i) {
        #pragma unroll
        for (int r = 0; r < 4; ++r) {
          int m = mtile + wr * 64 + i * 16 + lg * 4 + r;
          int bb = m >> 11, t = m & 2047;
          dst[(size_t)((bb * 16 + h) * 2048 + t) * 64 + d] = f2bf((acc[i][j][r] + bv) * sc);
        }
      }
    }
  }
}

// ---- flash attention v9: v6 4-wave kv-split + K prefetch in NAMED registers
//      (no arrays -> no scratch; v8 post-mortem), V loads hoisted to step entry ----
__device__ __forceinline__ void attn_compute(bf16x8 kf0, bf16x8 kf1, bf16x8 kf2, bf16x8 kf3,
                                             const short* __restrict__ vp,
                                             const bf16x8* qf,
                                             f32x16& y0, f32x16& y1,
                                             float& m, float& li,
                                             int lq, int hl, bool diag) {
  // issue V loads immediately (consumed ~QK+softmax later)
  uint4 vr0 = *reinterpret_cast<const uint4*>(vp);
  uint4 vr1 = *reinterpret_cast<const uint4*>(vp + 16);
  uint4 vr2 = *reinterpret_cast<const uint4*>(vp + 32 * 2048);
  uint4 vr3 = *reinterpret_cast<const uint4*>(vp + 32 * 2048 + 16);

  f32x16 s;
  #pragma unroll
  for (int r = 0; r < 16; ++r) s[r] = 0.f;
  __builtin_amdgcn_s_setprio(1);
  s = __builtin_amdgcn_mfma_f32_32x32x16_bf16(kf0, qf[0], s, 0, 0, 0);
  s = __builtin_amdgcn_mfma_f32_32x32x16_bf16(kf1, qf[1], s, 0, 0, 0);
  s = __builtin_amdgcn_mfma_f32_32x32x16_bf16(kf2, qf[2], s, 0, 0, 0);
  s = __builtin_amdgcn_mfma_f32_32x32x16_bf16(kf3, qf[3], s, 0, 0, 0);
  __builtin_amdgcn_s_setprio(0);
  if (diag) {
    #pragma unroll
    for (int r = 0; r < 16; ++r) {
      int kvl = (r & 3) + 8 * (r >> 2) + 4 * hl;
      if (kvl > lq) s[r] = -1e30f;
    }
  }
  float a0 = fmaxf(fmaxf(s[0], s[1]), fmaxf(s[2], s[3]));
  float a1 = fmaxf(fmaxf(s[4], s[5]), fmaxf(s[6], s[7]));
  float a2 = fmaxf(fmaxf(s[8], s[9]), fmaxf(s[10], s[11]));
  float a3 = fmaxf(fmaxf(s[12], s[13]), fmaxf(s[14], s[15]));
  float pm = fmaxf(fmaxf(a0, a1), fmaxf(a2, a3));
  pm = fmaxf(pm, __shfl_xor(pm, 32));
  if (!__all(pm - m <= 8.0f)) {
    float mn = fmaxf(m, pm);
    float sc = __builtin_amdgcn_exp2f(m - mn);
    m = mn;
    li *= sc;
    #pragma unroll
    for (int r = 0; r < 16; ++r) { y0[r] *= sc; y1[r] *= sc; }
  }
  unsigned u[8];
  float rs = 0.f;
  #pragma unroll
  for (int rq = 0; rq < 4; ++rq) {
    float p0 = __builtin_amdgcn_exp2f(s[4 * rq + 0] - m);
    float p1 = __builtin_amdgcn_exp2f(s[4 * rq + 1] - m);
    float p2 = __builtin_amdgcn_exp2f(s[4 * rq + 2] - m);
    float p3 = __builtin_amdgcn_exp2f(s[4 * rq + 3] - m);
    rs += (p0 + p1) + (p2 + p3);
    asm("v_cvt_pk_bf16_f32 %0, %1, %2" : "=v"(u[rq * 2 + 0]) : "v"(p0), "v"(p1));
    asm("v_cvt_pk_bf16_f32 %0, %1, %2" : "=v"(u[rq * 2 + 1]) : "v"(p2), "v"(p3));
  }
  rs += __shfl_xor(rs, 32);
  li += rs;
  asm volatile("v_permlane32_swap_b32 %0, %1" : "+v"(u[0]), "+v"(u[2]));
  asm volatile("v_permlane32_swap_b32 %0, %1" : "+v"(u[1]), "+v"(u[3]));
  asm volatile("v_permlane32_swap_b32 %0, %1" : "+v"(u[4]), "+v"(u[6]));
  asm volatile("v_permlane32_swap_b32 %0, %1" : "+v"(u[5]), "+v"(u[7]));
  uint32x4 w0 = {u[0], u[1], u[2], u[3]};
  uint32x4 w1 = {u[4], u[5], u[6], u[7]};
  bf16x8 pa0 = __builtin_bit_cast(bf16x8, w0);
  bf16x8 pa1 = __builtin_bit_cast(bf16x8, w1);
  __builtin_amdgcn_s_setprio(1);
  {
    bf16x8 vf00 = __builtin_bit_cast(bf16x8, vr0);
    bf16x8 vf01 = __builtin_bit_cast(bf16x8, vr1);
    bf16x8 vf10 = __builtin_bit_cast(bf16x8, vr2);
    bf16x8 vf11 = __builtin_bit_cast(bf16x8, vr3);
    y0 = __builtin_amdgcn_mfma_f32_32x32x16_bf16(vf00, pa0, y0, 0, 0, 0);
    y0 = __builtin_amdgcn_mfma_f32_32x32x16_bf16(vf01, pa1, y0, 0, 0, 0);
    y1 = __builtin_amdgcn_mfma_f32_32x32x16_bf16(vf10, pa0, y1, 0, 0, 0);
    y1 = __builtin_amdgcn_mfma_f32_32x32x16_bf16(vf11, pa1, y1, 0, 0, 0);
  }
  __builtin_amdgcn_s_setprio(0);
}

__global__ __launch_bounds__(256, 4) void attn_kernel(const short* __restrict__ q,
                                                      const short* __restrict__ k,
                                                      const short* __restrict__ vt,
                                                      short* __restrict__ y) {
  __shared__ float partL[3][8][64][4];   // 24 KB: partials of waves 1..3
  __shared__ float stm[4][32], stl[4][32];
  const int bid = blockIdx.x;
  const int t = 63 - (bid >> 5);           // longest-first
  const int b5 = bid & 31;
  const int bh = (b5 & 7) * 4 + (b5 >> 3); // group each bh's blocks on one XCD
  const int tid = threadIdx.x;
  const int w = tid >> 6;                  // wave: kv-split index 0..3
  const int l = tid & 63;
  const int lq = l & 31, hl = l >> 5;
  const short* qb = q + (size_t)bh * 131072;
  const short* kb = k + (size_t)bh * 131072;
  const short* vb = vt + (size_t)bh * 131072;   // [64][2048]

  // Q B-frags (k=64 -> 4 frags), shared q-tile for all 4 waves
  bf16x8 qf[4];
  {
    const short* qp = &qb[(size_t)(32 * t + lq) * 64 + hl * 8];
    #pragma unroll
    for (int ks = 0; ks < 4; ++ks)
      qf[ks] = *reinterpret_cast<const bf16x8*>(qp + ks * 16);
  }

  f32x16 y0, y1;
  #pragma unroll
  for (int r = 0; r < 16; ++r) { y0[r] = 0.f; y1[r] = 0.f; }
  float m = -1e30f, li = 0.f;

  // wave w handles kv tiles {w, w+4, ...} < t, plus diag tile t if t&3==w
  const short* kbase = kb + (size_t)lq * 64 + hl * 8;   // + tile*2048
  const short* vbase = vb + (size_t)lq * 2048 + hl * 8; // + tile*32
  const int cnt = (t > w) ? ((t - w + 3) >> 2) : 0;     // non-diag tiles
  const bool hd = ((t & 3) == w);
  const int n = cnt + (hd ? 1 : 0);
  auto tileof = [&](int i) { return (i < cnt) ? (w + 4 * i) : t; };

  // K prefetch pipeline in NAMED registers (no arrays -> no scratch)
  bf16x8 ck0, ck1, ck2, ck3;
  if (n > 0) {
    const short* kp = kbase + (size_t)tileof(0) * 2048;
    ck0 = *reinterpret_cast<const bf16x8*>(kp);
    ck1 = *reinterpret_cast<const bf16x8*>(kp + 16);
    ck2 = *reinterpret_cast<const bf16x8*>(kp + 32);
    ck3 = *reinterpret_cast<const bf16x8*>(kp + 48);
  }
  for (int i = 0; i < n; ++i) {
    bf16x8 nk0, nk1, nk2, nk3;
    if (i + 1 < n) {
      const short* kp = kbase + (size_t)tileof(i + 1) * 2048;
      nk0 = *reinterpret_cast<const bf16x8*>(kp);
      nk1 = *reinterpret_cast<const bf16x8*>(kp + 16);
      nk2 = *reinterpret_cast<const bf16x8*>(kp + 32);
      nk3 = *reinterpret_cast<const bf16x8*>(kp + 48);
    }
    attn_compute(ck0, ck1, ck2, ck3, vbase + tileof(i) * 32, qf,
                 y0, y1, m, li, lq, hl, hd && (i == n - 1));
    if (i + 1 < n) { ck0 = nk0; ck1 = nk1; ck2 = nk2; ck3 = nk3; }
  }

  // ---- merge the 4 wave-partials ----
  if (hl == 0) { stm[w][lq] = m; stl[w][lq] = li; }
  __syncthreads();
  float m0 = stm[0][lq], m1 = stm[1][lq], m2 = stm[2][lq], m3 = stm[3][lq];
  float M = fmaxf(fmaxf(m0, m1), fmaxf(m2, m3));
  float L = stl[0][lq] * __builtin_amdgcn_exp2f(m0 - M) +
            stl[1][lq] * __builtin_amdgcn_exp2f(m1 - M) +
            stl[2][lq] * __builtin_amdgcn_exp2f(m2 - M) +
            stl[3][lq] * __builtin_amdgcn_exp2f(m3 - M);
  float sc = __builtin_amdgcn_exp2f(m - M);
  #pragma unroll
  for (int r = 0; r < 16; ++r) { y0[r] *= sc; y1[r] *= sc; }
  if (w > 0) {
    #pragma unroll
    for (int c = 0; c < 4; ++c) {
      f32x4 v0 = {y0[4 * c + 0], y0[4 * c + 1], y0[4 * c + 2], y0[4 * c + 3]};
      f32x4 v1 = {y1[4 * c + 0], y1[4 * c + 1], y1[4 * c + 2], y1[4 * c + 3]};
      *reinterpret_cast<f32x4*>(&partL[w - 1][c][l][0]) = v0;
      *reinterpret_cast<f32x4*>(&partL[w - 1][c + 4][l][0]) = v1;
    }
  }
  __syncthreads();
  if (w == 0) {
    #pragma unroll
    for (int o = 0; o < 3; ++o)
      #pragma unroll
      for (int c = 0; c < 4; ++c) {
        f32x4 v0 = *reinterpret_cast<const f32x4*>(&partL[o][c][l][0]);
        f32x4 v1 = *reinterpret_cast<const f32x4*>(&partL[o][c + 4][l][0]);
        #pragma unroll
        for (int r = 0; r < 4; ++r) { y0[4 * c + r] += v0[r]; y1[4 * c + r] += v1[r]; }
      }
    float inv = 1.0f / L;
    int b_ = bh >> 4, h_ = bh & 15;
    short* yrow = &y[(size_t)(b_ * 2048 + 32 * t + lq) * 1024 + h_ * 64];
    #pragma unroll
    for (int dt = 0; dt < 2; ++dt) {
      const f32x16& yy = dt ? y1 : y0;
      #pragma unroll
      for (int rq = 0; rq < 4; ++rq) {
        int d0 = dt * 32 + 8 * rq + 4 * hl;
        uint2 pk;
        pk.x = (unsigned)(unsigned short)f2bf(yy[4 * rq + 0] * inv) |
               ((unsigned)(unsigned short)f2bf(yy[4 * rq + 1] * inv) << 16);
        pk.y = (unsigned)(unsigned short)f2bf(yy[4 * rq + 2] * inv) |
               ((unsigned)(unsigned short)f2bf(yy[4 * rq + 3] * inv) << 16);
        *reinterpret_cast<uint2*>(yrow + d0) = pk;
      }
    }
  }
}

// ---- GEMM3: out fp32 = y_bf[4096][1024] * Wproj_t[1024][1024]^T + bproj ----
__global__ __launch_bounds__(256) void gemm_proj(const short* __restrict__ A,
                                                 const short* __restrict__ Bt,
                                                 const float* __restrict__ bias,
                                                 float* __restrict__ out) {
  const int K = 1024;
  __shared__ short Al[8192];
  __shared__ short Bl[8192];
  int tid = threadIdx.x;
  int mtile = blockIdx.y * 128, ntile = blockIdx.x * 128;
  int w = tid >> 6, l = tid & 63;
  int wr = w >> 1, wc = w & 1;
  int lr = l & 15, lg = l >> 4;

  f32x4 zero4 = {0.f, 0.f, 0.f, 0.f};
  f32x4 acc[4][4];
  #pragma unroll
  for (int i = 0; i < 4; ++i)
    #pragma unroll
    for (int j = 0; j < 4; ++j) acc[i][j] = zero4;

  for (int k0 = 0; k0 < K; k0 += 64) {
    __syncthreads();
    #pragma unroll
    for (int c = 0; c < 4; ++c) {
      int idx = tid + c * 256;
      int row = idx >> 3, kc = idx & 7;
      gl_lds16(&A[(size_t)(mtile + row) * K + k0 + kc * 8], &Al[idx * 8]);
      gl_lds16(&Bt[(size_t)(ntile + row) * K + k0 + kc * 8], &Bl[idx * 8]);
    }
    __syncthreads();
    __builtin_amdgcn_s_setprio(1);
    #pragma unroll
    for (int kk = 0; kk < 2; ++kk) {
      bf16x8 af[4], bfr[4];
      #pragma unroll
      for (int i = 0; i < 4; ++i)
        af[i] = *reinterpret_cast<const bf16x8*>(&Al[(wr * 64 + i * 16 + lr) * 64 + kk * 32 + lg * 8]);
      #pragma unroll
      for (int j = 0; j < 4; ++j)
        bfr[j] = *reinterpret_cast<const bf16x8*>(&Bl[(wc * 64 + j * 16 + lr) * 64 + kk * 32 + lg * 8]);
      #pragma unroll
      for (int i = 0; i < 4; ++i)
        #pragma unroll
        for (int j = 0; j < 4; ++j)
          acc[i][j] = __builtin_amdgcn_mfma_f32_16x16x32_bf16(af[i], bfr[j], acc[i][j], 0, 0, 0);
    }
    __builtin_amdgcn_s_setprio(0);
  }

  #pragma unroll
  for (int j = 0; j < 4; ++j) {
    int n = ntile + wc * 64 + j * 16 + lr;
    float bv = bias[n];
    #pragma unroll
    for (int i = 0; i < 4; ++i) {
      #pragma unroll
      for (int r = 0; r < 4; ++r) {
        int m = mtile + wr * 64 + i * 16 + lg * 4 + r;
        out[(size_t)m * 1024 + n] = acc[i][j][r] + bv;
      }
    }
  }
}

extern "C" void kernel_launch(void* const* d_in, const int* in_sizes, int n_in,
                              void* d_out, int out_size, void* d_ws, size_t ws_size,
                              hipStream_t stream) {
  const float* x     = (const float*)d_in[0];
  const float* Wqkv  = (const float*)d_in[1];
  const float* bqkv  = (const float*)d_in[2];
  const float* Wproj = (const float*)d_in[3];
  const float* bproj = (const float*)d_in[4];
  float* out = (float*)d_out;

  const size_t M4 = 4096ull * 1024ull;
  short* ws = (short*)d_ws;
  short* x_bf    = ws;
  short* wqkv_t  = ws + M4;
  short* wproj_t = ws + M4 + 3ull * 1024 * 1024;
  short* qb      = wproj_t + 1024ull * 1024;
  short* kb      = qb + M4;
  short* vtb     = kb + M4;     // [bh][64][2048] transposed V
  short* yb      = x_bf;        // alias: x_bf dead after gemm_qkv

  cast_x_kernel<<<4096, 256, 0, stream>>>(x, x_bf, (int)(M4 / 4));
  transpose_cast<<<dim3(48, 16), 256, 0, stream>>>(Wqkv, wqkv_t, 1024, 3072);
  transpose_cast<<<dim3(16, 16), 256, 0, stream>>>(Wproj, wproj_t, 1024, 1024);
  gemm_qkv<<<dim3(24, 32), 256, 0, stream>>>(x_bf, wqkv_t, bqkv, qb, kb, vtb);
  attn_kernel<<<2048, 256, 0, stream>>>(qb, kb, vtb, yb);
  gemm_proj<<<dim3(8, 32), 256, 0, stream>>>(yb, wproj_t, bproj, out);
}

// Round 11
// 164.563 us; speedup vs baseline: 1.3525x; 1.0243x over previous
//
#include <hip/hip_runtime.h>

// ---- types ----
typedef __bf16 bf16x8 __attribute__((ext_vector_type(8)));
typedef float  f32x4  __attribute__((ext_vector_type(4)));
typedef float  f32x16 __attribute__((ext_vector_type(16)));
typedef unsigned int uint32x4 __attribute__((ext_vector_type(4)));

__device__ __forceinline__ short f2bf(float f) {
  union { float f; unsigned u; } v; v.f = f;
  unsigned r = v.u + 0x7fffu + ((v.u >> 16) & 1u);
  return (short)(r >> 16);
}

// keep a 16B value's registers live / pin load issue point (32-bit ties only)
#define PIN4(v) asm volatile("" : "+v"((v).x), "+v"((v).y), "+v"((v).z), "+v"((v).w))

// async global->LDS (16B per lane); LDS dest must be wave-uniform base + lane*16
__device__ __forceinline__ void gl_lds16(const short* g, short* l) {
  __builtin_amdgcn_global_load_lds((const __attribute__((address_space(1))) void*)g,
                                   (__attribute__((address_space(3))) void*)l, 16, 0, 0);
}

// ---- cast x fp32 -> bf16 (vectorized) ----
__global__ __launch_bounds__(256) void cast_x_kernel(const float* __restrict__ in,
                                                     short* __restrict__ out, int n4) {
  int i = blockIdx.x * 256 + threadIdx.x;
  if (i >= n4) return;
  float4 f = reinterpret_cast<const float4*>(in)[i];
  short4 o;
  o.x = f2bf(f.x); o.y = f2bf(f.y); o.z = f2bf(f.z); o.w = f2bf(f.w);
  reinterpret_cast<short4*>(out)[i] = o;
}

// ---- transpose + cast: in[R][Cc] fp32 -> out[Cc][R] bf16 ----
__global__ __launch_bounds__(256) void transpose_cast(const float* __restrict__ in,
                                                      short* __restrict__ out, int R, int Cc) {
  __shared__ short tile[64][65];
  int bx = blockIdx.x * 64;
  int by = blockIdx.y * 64;
  int tx = threadIdx.x & 63, ty = threadIdx.x >> 6;
  #pragma unroll
  for (int i = ty; i < 64; i += 4)
    tile[i][tx] = f2bf(in[(size_t)(by + i) * Cc + bx + tx]);
  __syncthreads();
  #pragma unroll
  for (int i = ty; i < 64; i += 4)
    out[(size_t)(bx + i) * R + by + tx] = tile[tx][i];
}

// ---- GEMM1: qkv = x_bf[4096][1024] * Wqkv_t[3072][1024]^T + bqkv
//      q,k -> [B2][H16][T2048][D64] bf16 (q scaled 0.125*log2e); v -> [BH][D64][T2048]
__global__ __launch_bounds__(256) void gemm_qkv(const short* __restrict__ A,
                                                const short* __restrict__ Bt,
                                                const float* __restrict__ bias,
                                                short* __restrict__ qo,
                                                short* __restrict__ ko,
                                                short* __restrict__ vt) {
  const int K = 1024;
  __shared__ short Al[8192];   // linear [128][64]
  __shared__ short Bl[8192];
  int tid = threadIdx.x;
  int mtile = blockIdx.y * 128, ntile = blockIdx.x * 128;
  int w = tid >> 6, l = tid & 63;
  int wr = w >> 1, wc = w & 1;
  int lr = l & 15, lg = l >> 4;

  f32x4 zero4 = {0.f, 0.f, 0.f, 0.f};
  f32x4 acc[4][4];
  #pragma unroll
  for (int i = 0; i < 4; ++i)
    #pragma unroll
    for (int j = 0; j < 4; ++j) acc[i][j] = zero4;

  for (int k0 = 0; k0 < K; k0 += 64) {
    __syncthreads();
    #pragma unroll
    for (int c = 0; c < 4; ++c) {
      int idx = tid + c * 256;
      int row = idx >> 3, kc = idx & 7;
      gl_lds16(&A[(size_t)(mtile + row) * K + k0 + kc * 8], &Al[idx * 8]);
      gl_lds16(&Bt[(size_t)(ntile + row) * K + k0 + kc * 8], &Bl[idx * 8]);
    }
    __syncthreads();
    __builtin_amdgcn_s_setprio(1);
    #pragma unroll
    for (int kk = 0; kk < 2; ++kk) {
      bf16x8 af[4], bfr[4];
      #pragma unroll
      for (int i = 0; i < 4; ++i)
        af[i] = *reinterpret_cast<const bf16x8*>(&Al[(wr * 64 + i * 16 + lr) * 64 + kk * 32 + lg * 8]);
      #pragma unroll
      for (int j = 0; j < 4; ++j)
        bfr[j] = *reinterpret_cast<const bf16x8*>(&Bl[(wc * 64 + j * 16 + lr) * 64 + kk * 32 + lg * 8]);
      #pragma unroll
      for (int i = 0; i < 4; ++i)
        #pragma unroll
        for (int j = 0; j < 4; ++j)
          acc[i][j] = __builtin_amdgcn_mfma_f32_16x16x32_bf16(af[i], bfr[j], acc[i][j], 0, 0, 0);
    }
    __builtin_amdgcn_s_setprio(0);
  }

  #pragma unroll
  for (int j = 0; j < 4; ++j) {
    int n = ntile + wc * 64 + j * 16 + lr;   // 0..3071 (sec uniform per block)
    float bv = bias[n];
    int sec = n >> 10;
    int ch = n & 1023;
    int h = ch >> 6, d = ch & 63;
    if (sec == 2) {
      #pragma unroll
      for (int i = 0; i < 4; ++i) {
        int t0g = mtile + wr * 64 + i * 16 + lg * 4;
        int bb = t0g >> 11, t = t0g & 2047;
        short4 pk;
        pk.x = f2bf(acc[i][j][0] + bv);
        pk.y = f2bf(acc[i][j][1] + bv);
        pk.z = f2bf(acc[i][j][2] + bv);
        pk.w = f2bf(acc[i][j][3] + bv);
        *reinterpret_cast<short4*>(&vt[((size_t)(bb * 16 + h) * 64 + d) * 2048 + t]) = pk;
      }
    } else {
      short* dst = (sec == 0) ? qo : ko;
      // q scaled by (1/sqrt(64)) * log2(e) so attention works in exp2 domain
      float sc = (sec == 0) ? 0.18033688f : 1.0f;
      #pragma unroll
      for (int i = 0; i < 4; ++i) {
        #pragma unroll
        for (int r = 0; r < 4; ++r) {
          int m = mtile + wr * 64 + i * 16 + lg * 4 + r;
          int bb = m >> 11, t = m & 2047;
          dst[(size_t)((bb * 16 + h) * 2048 + t) * 64 + d] = f2bf((acc[i][j][r] + bv) * sc);
        }
      }
    }
  }
}

// ---- flash attention v10b: v9 + PINNED register prefetch, component-wise 32-bit
//      asm ties (v10 compile fix: 128-bit "+v" ties unsupported) ----
__device__ __forceinline__ void attn_compute(bf16x8 kf0, bf16x8 kf1, bf16x8 kf2, bf16x8 kf3,
                                             const short* __restrict__ vp,
                                             const bf16x8* qf,
                                             f32x16& y0, f32x16& y1,
                                             float& m, float& li,
                                             int lq, int hl, bool diag) {
  // issue V loads immediately (consumed ~QK+softmax later); pin so they can't sink
  uint4 vr0 = *reinterpret_cast<const uint4*>(vp);
  uint4 vr1 = *reinterpret_cast<const uint4*>(vp + 16);
  uint4 vr2 = *reinterpret_cast<const uint4*>(vp + 32 * 2048);
  uint4 vr3 = *reinterpret_cast<const uint4*>(vp + 32 * 2048 + 16);
  PIN4(vr0); PIN4(vr1); PIN4(vr2); PIN4(vr3);

  f32x16 s;
  #pragma unroll
  for (int r = 0; r < 16; ++r) s[r] = 0.f;
  __builtin_amdgcn_s_setprio(1);
  s = __builtin_amdgcn_mfma_f32_32x32x16_bf16(kf0, qf[0], s, 0, 0, 0);
  s = __builtin_amdgcn_mfma_f32_32x32x16_bf16(kf1, qf[1], s, 0, 0, 0);
  s = __builtin_amdgcn_mfma_f32_32x32x16_bf16(kf2, qf[2], s, 0, 0, 0);
  s = __builtin_amdgcn_mfma_f32_32x32x16_bf16(kf3, qf[3], s, 0, 0, 0);
  __builtin_amdgcn_s_setprio(0);
  if (diag) {
    #pragma unroll
    for (int r = 0; r < 16; ++r) {
      int kvl = (r & 3) + 8 * (r >> 2) + 4 * hl;
      if (kvl > lq) s[r] = -1e30f;
    }
  }
  float a0 = fmaxf(fmaxf(s[0], s[1]), fmaxf(s[2], s[3]));
  float a1 = fmaxf(fmaxf(s[4], s[5]), fmaxf(s[6], s[7]));
  float a2 = fmaxf(fmaxf(s[8], s[9]), fmaxf(s[10], s[11]));
  float a3 = fmaxf(fmaxf(s[12], s[13]), fmaxf(s[14], s[15]));
  float pm = fmaxf(fmaxf(a0, a1), fmaxf(a2, a3));
  pm = fmaxf(pm, __shfl_xor(pm, 32));
  if (!__all(pm - m <= 8.0f)) {
    float mn = fmaxf(m, pm);
    float sc = __builtin_amdgcn_exp2f(m - mn);
    m = mn;
    li *= sc;
    #pragma unroll
    for (int r = 0; r < 16; ++r) { y0[r] *= sc; y1[r] *= sc; }
  }
  unsigned u[8];
  float rs = 0.f;
  #pragma unroll
  for (int rq = 0; rq < 4; ++rq) {
    float p0 = __builtin_amdgcn_exp2f(s[4 * rq + 0] - m);
    float p1 = __builtin_amdgcn_exp2f(s[4 * rq + 1] - m);
    float p2 = __builtin_amdgcn_exp2f(s[4 * rq + 2] - m);
    float p3 = __builtin_amdgcn_exp2f(s[4 * rq + 3] - m);
    rs += (p0 + p1) + (p2 + p3);
    asm("v_cvt_pk_bf16_f32 %0, %1, %2" : "=v"(u[rq * 2 + 0]) : "v"(p0), "v"(p1));
    asm("v_cvt_pk_bf16_f32 %0, %1, %2" : "=v"(u[rq * 2 + 1]) : "v"(p2), "v"(p3));
  }
  rs += __shfl_xor(rs, 32);
  li += rs;
  asm volatile("v_permlane32_swap_b32 %0, %1" : "+v"(u[0]), "+v"(u[2]));
  asm volatile("v_permlane32_swap_b32 %0, %1" : "+v"(u[1]), "+v"(u[3]));
  asm volatile("v_permlane32_swap_b32 %0, %1" : "+v"(u[4]), "+v"(u[6]));
  asm volatile("v_permlane32_swap_b32 %0, %1" : "+v"(u[5]), "+v"(u[7]));
  uint32x4 w0 = {u[0], u[1], u[2], u[3]};
  uint32x4 w1 = {u[4], u[5], u[6], u[7]};
  bf16x8 pa0 = __builtin_bit_cast(bf16x8, w0);
  bf16x8 pa1 = __builtin_bit_cast(bf16x8, w1);
  __builtin_amdgcn_s_setprio(1);
  {
    bf16x8 vf00 = __builtin_bit_cast(bf16x8, vr0);
    bf16x8 vf01 = __builtin_bit_cast(bf16x8, vr1);
    bf16x8 vf10 = __builtin_bit_cast(bf16x8, vr2);
    bf16x8 vf11 = __builtin_bit_cast(bf16x8, vr3);
    y0 = __builtin_amdgcn_mfma_f32_32x32x16_bf16(vf00, pa0, y0, 0, 0, 0);
    y0 = __builtin_amdgcn_mfma_f32_32x32x16_bf16(vf01, pa1, y0, 0, 0, 0);
    y1 = __builtin_amdgcn_mfma_f32_32x32x16_bf16(vf10, pa0, y1, 0, 0, 0);
    y1 = __builtin_amdgcn_mfma_f32_32x32x16_bf16(vf11, pa1, y1, 0, 0, 0);
  }
  __builtin_amdgcn_s_setprio(0);
}

__global__ __launch_bounds__(256, 4) void attn_kernel(const short* __restrict__ q,
                                                      const short* __restrict__ k,
                                                      const short* __restrict__ vt,
                                                      short* __restrict__ y) {
  __shared__ float partL[3][8][64][4];   // 24 KB: partials of waves 1..3
  __shared__ float stm[4][32], stl[4][32];
  const int bid = blockIdx.x;
  const int t = 63 - (bid >> 5);           // longest-first
  const int b5 = bid & 31;
  const int bh = (b5 & 7) * 4 + (b5 >> 3); // group each bh's blocks on one XCD
  const int tid = threadIdx.x;
  const int w = tid >> 6;                  // wave: kv-split index 0..3
  const int l = tid & 63;
  const int lq = l & 31, hl = l >> 5;
  const short* qb = q + (size_t)bh * 131072;
  const short* kb = k + (size_t)bh * 131072;
  const short* vb = vt + (size_t)bh * 131072;   // [64][2048]

  // Q B-frags (k=64 -> 4 frags), shared q-tile for all 4 waves
  bf16x8 qf[4];
  {
    const short* qp = &qb[(size_t)(32 * t + lq) * 64 + hl * 8];
    #pragma unroll
    for (int ks = 0; ks < 4; ++ks)
      qf[ks] = *reinterpret_cast<const bf16x8*>(qp + ks * 16);
  }

  f32x16 y0, y1;
  #pragma unroll
  for (int r = 0; r < 16; ++r) { y0[r] = 0.f; y1[r] = 0.f; }
  float m = -1e30f, li = 0.f;

  // wave w handles kv tiles {w, w+4, ...} < t, plus diag tile t if t&3==w
  const short* kbase = kb + (size_t)lq * 64 + hl * 8;   // + tile*2048
  const short* vbase = vb + (size_t)lq * 2048 + hl * 8; // + tile*32
  const int cnt = (t > w) ? ((t - w + 3) >> 2) : 0;     // non-diag tiles
  const bool hd = ((t & 3) == w);
  const int n = cnt + (hd ? 1 : 0);
  auto tileof = [&](int i) { return (i < cnt) ? (w + 4 * i) : t; };

  // K prefetch pipeline: named uint4 registers + component pins + sched fence
  uint4 ck0, ck1, ck2, ck3;
  if (n > 0) {
    const short* kp = kbase + (size_t)tileof(0) * 2048;
    ck0 = *reinterpret_cast<const uint4*>(kp);
    ck1 = *reinterpret_cast<const uint4*>(kp + 16);
    ck2 = *reinterpret_cast<const uint4*>(kp + 32);
    ck3 = *reinterpret_cast<const uint4*>(kp + 48);
  }
  for (int i = 0; i < n; ++i) {
    uint4 nk0 = ck0, nk1 = ck1, nk2 = ck2, nk3 = ck3;
    if (i + 1 < n) {
      const short* kp = kbase + (size_t)tileof(i + 1) * 2048;
      nk0 = *reinterpret_cast<const uint4*>(kp);
      nk1 = *reinterpret_cast<const uint4*>(kp + 16);
      nk2 = *reinterpret_cast<const uint4*>(kp + 32);
      nk3 = *reinterpret_cast<const uint4*>(kp + 48);
      // pin: loads must be issued here, results live across the compute below
      PIN4(nk0); PIN4(nk1); PIN4(nk2); PIN4(nk3);
      __builtin_amdgcn_sched_barrier(0);
    }
    attn_compute(__builtin_bit_cast(bf16x8, ck0), __builtin_bit_cast(bf16x8, ck1),
                 __builtin_bit_cast(bf16x8, ck2), __builtin_bit_cast(bf16x8, ck3),
                 vbase + tileof(i) * 32, qf,
                 y0, y1, m, li, lq, hl, hd && (i == n - 1));
    ck0 = nk0; ck1 = nk1; ck2 = nk2; ck3 = nk3;
  }

  // ---- merge the 4 wave-partials ----
  if (hl == 0) { stm[w][lq] = m; stl[w][lq] = li; }
  __syncthreads();
  float m0 = stm[0][lq], m1 = stm[1][lq], m2 = stm[2][lq], m3 = stm[3][lq];
  float M = fmaxf(fmaxf(m0, m1), fmaxf(m2, m3));
  float L = stl[0][lq] * __builtin_amdgcn_exp2f(m0 - M) +
            stl[1][lq] * __builtin_amdgcn_exp2f(m1 - M) +
            stl[2][lq] * __builtin_amdgcn_exp2f(m2 - M) +
            stl[3][lq] * __builtin_amdgcn_exp2f(m3 - M);
  float sc = __builtin_amdgcn_exp2f(m - M);
  #pragma unroll
  for (int r = 0; r < 16; ++r) { y0[r] *= sc; y1[r] *= sc; }
  if (w > 0) {
    #pragma unroll
    for (int c = 0; c < 4; ++c) {
      f32x4 v0 = {y0[4 * c + 0], y0[4 * c + 1], y0[4 * c + 2], y0[4 * c + 3]};
      f32x4 v1 = {y1[4 * c + 0], y1[4 * c + 1], y1[4 * c + 2], y1[4 * c + 3]};
      *reinterpret_cast<f32x4*>(&partL[w - 1][c][l][0]) = v0;
      *reinterpret_cast<f32x4*>(&partL[w - 1][c + 4][l][0]) = v1;
    }
  }
  __syncthreads();
  if (w == 0) {
    #pragma unroll
    for (int o = 0; o < 3; ++o)
      #pragma unroll
      for (int c = 0; c < 4; ++c) {
        f32x4 v0 = *reinterpret_cast<const f32x4*>(&partL[o][c][l][0]);
        f32x4 v1 = *reinterpret_cast<const f32x4*>(&partL[o][c + 4][l][0]);
        #pragma unroll
        for (int r = 0; r < 4; ++r) { y0[4 * c + r] += v0[r]; y1[4 * c + r] += v1[r]; }
      }
    float inv = 1.0f / L;
    int b_ = bh >> 4, h_ = bh & 15;
    short* yrow = &y[(size_t)(b_ * 2048 + 32 * t + lq) * 1024 + h_ * 64];
    #pragma unroll
    for (int dt = 0; dt < 2; ++dt) {
      const f32x16& yy = dt ? y1 : y0;
      #pragma unroll
      for (int rq = 0; rq < 4; ++rq) {
        int d0 = dt * 32 + 8 * rq + 4 * hl;
        uint2 pk;
        pk.x = (unsigned)(unsigned short)f2bf(yy[4 * rq + 0] * inv) |
               ((unsigned)(unsigned short)f2bf(yy[4 * rq + 1] * inv) << 16);
        pk.y = (unsigned)(unsigned short)f2bf(yy[4 * rq + 2] * inv) |
               ((unsigned)(unsigned short)f2bf(yy[4 * rq + 3] * inv) << 16);
        *reinterpret_cast<uint2*>(yrow + d0) = pk;
      }
    }
  }
}

// ---- GEMM3: out fp32 = y_bf[4096][1024] * Wproj_t[1024][1024]^T + bproj ----
__global__ __launch_bounds__(256) void gemm_proj(const short* __restrict__ A,
                                                 const short* __restrict__ Bt,
                                                 const float* __restrict__ bias,
                                                 float* __restrict__ out) {
  const int K = 1024;
  __shared__ short Al[8192];
  __shared__ short Bl[8192];
  int tid = threadIdx.x;
  int mtile = blockIdx.y * 128, ntile = blockIdx.x * 128;
  int w = tid >> 6, l = tid & 63;
  int wr = w >> 1, wc = w & 1;
  int lr = l & 15, lg = l >> 4;

  f32x4 zero4 = {0.f, 0.f, 0.f, 0.f};
  f32x4 acc[4][4];
  #pragma unroll
  for (int i = 0; i < 4; ++i)
    #pragma unroll
    for (int j = 0; j < 4; ++j) acc[i][j] = zero4;

  for (int k0 = 0; k0 < K; k0 += 64) {
    __syncthreads();
    #pragma unroll
    for (int c = 0; c < 4; ++c) {
      int idx = tid + c * 256;
      int row = idx >> 3, kc = idx & 7;
      gl_lds16(&A[(size_t)(mtile + row) * K + k0 + kc * 8], &Al[idx * 8]);
      gl_lds16(&Bt[(size_t)(ntile + row) * K + k0 + kc * 8], &Bl[idx * 8]);
    }
    __syncthreads();
    __builtin_amdgcn_s_setprio(1);
    #pragma unroll
    for (int kk = 0; kk < 2; ++kk) {
      bf16x8 af[4], bfr[4];
      #pragma unroll
      for (int i = 0; i < 4; ++i)
        af[i] = *reinterpret_cast<const bf16x8*>(&Al[(wr * 64 + i * 16 + lr) * 64 + kk * 32 + lg * 8]);
      #pragma unroll
      for (int j = 0; j < 4; ++j)
        bfr[j] = *reinterpret_cast<const bf16x8*>(&Bl[(wc * 64 + j * 16 + lr) * 64 + kk * 32 + lg * 8]);
      #pragma unroll
      for (int i = 0; i < 4; ++i)
        #pragma unroll
        for (int j = 0; j < 4; ++j)
          acc[i][j] = __builtin_amdgcn_mfma_f32_16x16x32_bf16(af[i], bfr[j], acc[i][j], 0, 0, 0);
    }
    __builtin_amdgcn_s_setprio(0);
  }

  #pragma unroll
  for (int j = 0; j < 4; ++j) {
    int n = ntile + wc * 64 + j * 16 + lr;
    float bv = bias[n];
    #pragma unroll
    for (int i = 0; i < 4; ++i) {
      #pragma unroll
      for (int r = 0; r < 4; ++r) {
        int m = mtile + wr * 64 + i * 16 + lg * 4 + r;
        out[(size_t)m * 1024 + n] = acc[i][j][r] + bv;
      }
    }
  }
}

extern "C" void kernel_launch(void* const* d_in, const int* in_sizes, int n_in,
                              void* d_out, int out_size, void* d_ws, size_t ws_size,
                              hipStream_t stream) {
  const float* x     = (const float*)d_in[0];
  const float* Wqkv  = (const float*)d_in[1];
  const float* bqkv  = (const float*)d_in[2];
  const float* Wproj = (const float*)d_in[3];
  const float* bproj = (const float*)d_in[4];
  float* out = (float*)d_out;

  const size_t M4 = 4096ull * 1024ull;
  short* ws = (short*)d_ws;
  short* x_bf    = ws;
  short* wqkv_t  = ws + M4;
  short* wproj_t = ws + M4 + 3ull * 1024 * 1024;
  short* qb      = wproj_t + 1024ull * 1024;
  short* kb      = qb + M4;
  short* vtb     = kb + M4;     // [bh][64][2048] transposed V
  short* yb      = x_bf;        // alias: x_bf dead after gemm_qkv

  cast_x_kernel<<<4096, 256, 0, stream>>>(x, x_bf, (int)(M4 / 4));
  transpose_cast<<<dim3(48, 16), 256, 0, stream>>>(Wqkv, wqkv_t, 1024, 3072);
  transpose_cast<<<dim3(16, 16), 256, 0, stream>>>(Wproj, wproj_t, 1024, 1024);
  gemm_qkv<<<dim3(24, 32), 256, 0, stream>>>(x_bf, wqkv_t, bqkv, qb, kb, vtb);
  attn_kernel<<<2048, 256, 0, stream>>>(qb, kb, vtb, yb);
  gemm_proj<<<dim3(8, 32), 256, 0, stream>>>(yb, wproj_t, bproj, out);
}